// Round 18
// baseline (135.591 us; speedup 1.0000x reference)
//
#include <hip/hip_runtime.h>
#include <hip/hip_fp16.h>
#include <hip/hip_fp8.h>
#include <math.h>

#define N_NODES 100000
#define N_EDGES 1000000
#define QKV_BLOCKS ((N_NODES + 63) / 64)      // 1563
#define FILL_BLOCKS ((N_EDGES + 255) / 256)   // 3907 (1 edge/thread)
#define PREP_BLOCKS 96                        // 24576 weight elems / 256
#define HEAD_BLOCKS 98                        // 25000 int4 stores / 256
#define AGG_BLOCKS ((N_NODES + 63) / 64)      // 1563 (64 nodes/block)
#define KV_STRIDE 192                         // 64B fp8 K + 128B fp16 V
// IN=64, TD=64, OUT=64, H=4, HD=16

typedef __attribute__((ext_vector_type(8))) _Float16 f16x8;
typedef __attribute__((ext_vector_type(4))) float    f32x4;

// ---------------------------------------------------------------------------
// Dispatch 1: weight transpose+fp16 (96 blocks) + head[]=-1 init (98 blocks).
// ---------------------------------------------------------------------------
__global__ __launch_bounds__(256) void prep_kernel(
    const float* __restrict__ qw, const float* __restrict__ kw,
    const float* __restrict__ vw, const float* __restrict__ ow,
    _Float16* __restrict__ WqT, _Float16* __restrict__ WkT,
    _Float16* __restrict__ WvT, _Float16* __restrict__ WoT,
    int* __restrict__ head)
{
    if (blockIdx.x < PREP_BLOCKS) {
        const int idx = blockIdx.x * 256 + threadIdx.x;   // 0..24575
        if (idx < 8192) {
            const int c = idx >> 7, k = idx & 127;
            WqT[idx] = (_Float16)qw[k * 64 + c];
        } else if (idx < 16384) {
            const int i = idx - 8192, c = i >> 7, k = i & 127;
            WkT[i] = (_Float16)kw[k * 64 + c];
        } else if (idx < 20480) {
            const int i = idx - 16384, c = i >> 6, k = i & 63;
            WvT[i] = (_Float16)vw[k * 64 + c];
        } else {
            const int i = idx - 20480, c = i >> 6, k = i & 63;
            WoT[i] = (_Float16)ow[k * 64 + c];
        }
    } else {
        const int idx = (blockIdx.x - PREP_BLOCKS) * 256 + threadIdx.x;
        if (idx < N_NODES / 4)                 // 25000 int4 = 100000 ints
            ((int4*)head)[idx] = make_int4(-1, -1, -1, -1);
    }
}

// ---------------------------------------------------------------------------
// Dispatch 2: QKV-MFMA (1563 blocks, first) || linked-list fill (3907 blocks).
// fill: old = atomicExch(&head[d], e); next2[e] = {old, src[e]} (coalesced).
// ~65us = device returning-atomic wall (probed r10-r16); qkv hides under it.
// qkv: m89-verified MFMA. K stored fp8 e4m3 (agg gather -25% bytes), V fp16,
// packed per node: KV[node*192 .. ] = [K fp8 x64 | V fp16 x64].
// ---------------------------------------------------------------------------
__global__ __launch_bounds__(256) void fill_qkv_kernel(
    const int* __restrict__ src, const int* __restrict__ dst,
    int* __restrict__ head, int2* __restrict__ next2,
    const float* __restrict__ x, const float* __restrict__ tf,
    const _Float16* __restrict__ WqT, const _Float16* __restrict__ WkT,
    const _Float16* __restrict__ WvT,
    const float* __restrict__ qb, const float* __restrict__ kb,
    const float* __restrict__ vb,
    _Float16* __restrict__ Qh, char* __restrict__ KV)
{
    __shared__ _Float16 xt[64][128];     // 16 KB (fill blocks ignore it)
    const int t = threadIdx.x;

    if (blockIdx.x >= QKV_BLOCKS) {
        const int e = (blockIdx.x - QKV_BLOCKS) * 256 + t;
        if (e < N_EDGES) {
            const int d  = dst[e];
            const int sv = src[e];
            const int old = atomicExch(&head[d], e);
            next2[e] = make_int2(old, sv);
        }
        return;
    }

    const int base = blockIdx.x * 64;

    // stage [x|tf] -> LDS f16, swizzled groups
    {
        const int j = t & 15;
        #pragma unroll
        for (int i = 0; i < 4; ++i) {
            const int r = (t >> 4) + 16 * i;
            int node = base + r;
            if (node >= N_NODES) node = N_NODES - 1;   // clamp; stores guarded
            const float* p = (j < 8) ? (x  + (size_t)node * 64 + 8 * j)
                                     : (tf + (size_t)node * 64 + 8 * (j - 8));
            const float4 lo = ((const float4*)p)[0];
            const float4 hi = ((const float4*)p)[1];
            f16x8 h = { (_Float16)lo.x, (_Float16)lo.y, (_Float16)lo.z,
                        (_Float16)lo.w, (_Float16)hi.x, (_Float16)hi.y,
                        (_Float16)hi.z, (_Float16)hi.w };
            const int js = j ^ (r & 15);
            *(f16x8*)&xt[r][js * 8] = h;
        }
    }

    const int wave = t >> 6;
    const int lane = t & 63;
    const int lrow = lane & 15;
    const int lgrp = lane >> 4;
    const int cw   = wave * 16;

    f16x8 bq[4], bk[4], bv[2];
    const float biasq = qb[cw + lrow];
    const float biask = kb[cw + lrow];
    const float biasv = vb[cw + lrow];
    {
        const size_t rq = (size_t)(cw + lrow) * 128 + lgrp * 8;
        #pragma unroll
        for (int kt = 0; kt < 4; ++kt) {
            bq[kt] = *(const f16x8*)&WqT[rq + kt * 32];
            bk[kt] = *(const f16x8*)&WkT[rq + kt * 32];
        }
        const size_t rv = (size_t)(cw + lrow) * 64 + lgrp * 8;
        #pragma unroll
        for (int kt = 0; kt < 2; ++kt)
            bv[kt] = *(const f16x8*)&WvT[rv + kt * 32];
    }
    __syncthreads();

    #pragma unroll
    for (int rt = 0; rt < 4; ++rt) {
        f16x8 a[4];
        const int r = rt * 16 + lrow;
        #pragma unroll
        for (int kt = 0; kt < 4; ++kt) {
            const int js = (kt * 4 + lgrp) ^ lrow;
            a[kt] = *(const f16x8*)&xt[r][js * 8];
        }
        f32x4 accq = {0.f, 0.f, 0.f, 0.f};
        f32x4 acck = {0.f, 0.f, 0.f, 0.f};
        f32x4 accv = {0.f, 0.f, 0.f, 0.f};
        #pragma unroll
        for (int kt = 0; kt < 4; ++kt) {
            accq = __builtin_amdgcn_mfma_f32_16x16x32_f16(a[kt], bq[kt], accq, 0, 0, 0);
            acck = __builtin_amdgcn_mfma_f32_16x16x32_f16(a[kt], bk[kt], acck, 0, 0, 0);
        }
        #pragma unroll
        for (int kt = 0; kt < 2; ++kt)
            accv = __builtin_amdgcn_mfma_f32_16x16x32_f16(a[kt], bv[kt], accv, 0, 0, 0);
        #pragma unroll
        for (int rr = 0; rr < 4; ++rr) {
            const int node = base + rt * 16 + lgrp * 4 + rr;
            if (node < N_NODES) {
                Qh[(size_t)node * 64 + cw + lrow] = (_Float16)(accq[rr] + biasq);
                char* rowp = KV + (size_t)node * KV_STRIDE;
                ((__hip_fp8_e4m3*)rowp)[cw + lrow] =
                    __hip_fp8_e4m3(acck[rr] + biask);
                ((_Float16*)(rowp + 64))[cw + lrow] = (_Float16)(accv[rr] + biasv);
            }
        }
    }
}

// ---------------------------------------------------------------------------
// Dispatch 3: gather-aggregate + normalize + MFMA output GEMM, fused.
// 64 nodes/block, 4 waves x 16 nodes, work-pool (r15) + next2 prefetch (r17).
// K gathered as fp8 (8B per sublane), V fp16 (16B): 192B/edge vs 256B.
// ---------------------------------------------------------------------------
__global__ __launch_bounds__(256) void agg_kernel(
    const int* __restrict__ head, const int2* __restrict__ next2,
    const __half* __restrict__ Qh, const char* __restrict__ KV,
    const _Float16* __restrict__ WoT, const float* __restrict__ ob,
    float* __restrict__ out)
{
    __shared__ _Float16 aggh[64][64];     // 8 KB
    __shared__ int pool[4];
    const int t    = threadIdx.x;
    const int wave = t >> 6;
    const int lane = t & 63;
    const int g    = lane >> 3;        // slot 0..7
    const int s    = lane & 7;         // sublane: cols 8s..8s+7
    const int lrow = lane & 15;        // MFMA A-row / D-col
    const int lgrp = lane >> 4;        // MFMA k-group
    const int cw   = wave * 16;        // out col tile base
    const int nb   = blockIdx.x * 64;
    const int wbase = wave * 16;       // wave's row base

    if (lane == 0) pool[wave] = 8;

    f16x8 bo0, bo1;
    {
        const size_t ro = (size_t)(cw + lrow) * 64 + lgrp * 8;
        bo0 = *(const f16x8*)&WoT[ro];
        bo1 = *(const f16x8*)&WoT[ro + 32];
    }
    const float biaso = ob[cw + lrow];
    __syncthreads();                   // pool init visible

    const uint4* __restrict__ Q4 = (const uint4*)Qh;

    int   idx  = g;
    int   cur  = nb + wbase + idx;
    int   e    = (cur < N_NODES) ? head[cur] : -1;
    int2  sn   = next2[(e >= 0) ? e : 0];   // current hop (dummy-safe)
    bool  done = false;
    float acc[8] = {0.f, 0.f, 0.f, 0.f, 0.f, 0.f, 0.f, 0.f};
    float ssum = 0.f;
    float qf[8];
    {
        const int qn = (cur < N_NODES) ? cur : 0;
        const uint4 qu = Q4[(size_t)qn * 8 + s];
        const __half2* qh = (const __half2*)&qu;
        #pragma unroll
        for (int j = 0; j < 4; ++j) {
            const float2 a = __half22float2(qh[j]);
            qf[2 * j] = a.x; qf[2 * j + 1] = a.y;
        }
    }

    for (;;) {
        while (e < 0 && !done) {
            const float inv = (ssum > 0.f) ? (1.0f / ssum) : 0.0f;
            const int r = wbase + idx;
            f16x8 h = { (_Float16)(acc[0] * inv), (_Float16)(acc[1] * inv),
                        (_Float16)(acc[2] * inv), (_Float16)(acc[3] * inv),
                        (_Float16)(acc[4] * inv), (_Float16)(acc[5] * inv),
                        (_Float16)(acc[6] * inv), (_Float16)(acc[7] * inv) };
            *(f16x8*)&aggh[r][(s ^ (r & 7)) * 8] = h;

            int tkt = 0;
            if (s == 0) tkt = atomicAdd(&pool[wave], 1);
            tkt = __shfl(tkt, g * 8);
            if (tkt < 16) {
                idx = tkt;
                cur = nb + wbase + idx;
                e   = (cur < N_NODES) ? head[cur] : -1;
                sn  = next2[(e >= 0) ? e : 0];
                const int qn = (cur < N_NODES) ? cur : 0;
                const uint4 qu = Q4[(size_t)qn * 8 + s];
                const __half2* qh = (const __half2*)&qu;
                #pragma unroll
                for (int j = 0; j < 4; ++j) {
                    const float2 a = __half22float2(qh[j]);
                    qf[2 * j] = a.x; qf[2 * j + 1] = a.y;
                }
                #pragma unroll
                for (int j = 0; j < 8; ++j) acc[j] = 0.f;
                ssum = 0.f;
            } else {
                done = true;
            }
        }
        if (__all(done)) break;

        const bool act = (e >= 0);
        const int  sv  = act ? sn.y : 0;     // src node (dummy 0 if inactive)
        const int  en  = act ? sn.x : -1;    // next edge in chain

        // PREFETCH next hop's {next,src}; overlaps the K/V gather below
        const int2 snn = next2[(en >= 0) ? en : 0];

        const char* rowp = KV + (size_t)sv * KV_STRIDE;
        const unsigned long long k8 =
            *(const unsigned long long*)(rowp + (size_t)s * 8);      // 8 fp8
        const uint4 vu = *(const uint4*)(rowp + 64 + (size_t)s * 16); // 8 fp16

        float kf[8], vf[8];
        #pragma unroll
        for (int j = 0; j < 8; ++j) {
            __hip_fp8_e4m3 kq;
            kq.__x = (__hip_fp8_storage_t)((k8 >> (8 * j)) & 0xffull);
            kf[j] = (float)kq;
        }
        {
            const __half2* vh = (const __half2*)&vu;
            #pragma unroll
            for (int j = 0; j < 4; ++j) {
                const float2 b = __half22float2(vh[j]);
                vf[2 * j] = b.x; vf[2 * j + 1] = b.y;
            }
        }
        float dq = qf[0] * kf[0] + qf[1] * kf[1] + qf[2] * kf[2] + qf[3] * kf[3]
                 + qf[4] * kf[4] + qf[5] * kf[5] + qf[6] * kf[6] + qf[7] * kf[7];
        dq += __shfl_xor(dq, 1);             // pair (2h,2h+1): full head dot
        const float p = act ? __expf(dq * 0.25f) : 0.f;   // 1/sqrt(16)
        ssum += p;
        #pragma unroll
        for (int j = 0; j < 8; ++j) acc[j] = fmaf(p, vf[j], acc[j]);

        e  = act ? en : -1;
        sn = snn;
    }
    __syncthreads();

    // out tile [64 nodes][64 cols] = aggh @ WoT ; wave w -> cols 16w..16w+15
    #pragma unroll
    for (int rt = 0; rt < 4; ++rt) {
        const int r = rt * 16 + lrow;
        f16x8 a0 = *(const f16x8*)&aggh[r][((lgrp)     ^ (lrow & 7)) * 8];
        f16x8 a1 = *(const f16x8*)&aggh[r][((4 + lgrp) ^ (lrow & 7)) * 8];
        f32x4 acco = {0.f, 0.f, 0.f, 0.f};
        acco = __builtin_amdgcn_mfma_f32_16x16x32_f16(a0, bo0, acco, 0, 0, 0);
        acco = __builtin_amdgcn_mfma_f32_16x16x32_f16(a1, bo1, acco, 0, 0, 0);
        #pragma unroll
        for (int rr = 0; rr < 4; ++rr) {
            const int n = nb + rt * 16 + lgrp * 4 + rr;
            if (n < N_NODES)
                out[(size_t)n * 64 + cw + lrow] = acco[rr] + biaso;
        }
    }
}

// ---------------------------------------------------------------------------
extern "C" void kernel_launch(void* const* d_in, const int* in_sizes, int n_in,
                              void* d_out, int out_size, void* d_ws, size_t ws_size,
                              hipStream_t stream) {
    const float* x  = (const float*)d_in[0];
    const float* tf = (const float*)d_in[1];
    const int*   ei = (const int*)  d_in[2];
    const float* qw = (const float*)d_in[3];
    const float* qb = (const float*)d_in[4];
    const float* kw = (const float*)d_in[5];
    const float* kb = (const float*)d_in[6];
    const float* vw = (const float*)d_in[7];
    const float* vb = (const float*)d_in[8];
    const float* ow = (const float*)d_in[9];
    const float* ob = (const float*)d_in[10];
    float* out = (float*)d_out;

    char* ws = (char*)d_ws;
    const size_t qsz  = (size_t)N_NODES * 64 * sizeof(_Float16);   // 12.8 MB
    const size_t kvsz = (size_t)N_NODES * KV_STRIDE;               // 19.2 MB

    _Float16* Qh      = (_Float16*)(ws);
    char*     KV      = ws + qsz;
    _Float16* WqT     = (_Float16*)(ws + qsz + kvsz);    // 8192 halves
    _Float16* WkT     = WqT + 8192;                       // 8192
    _Float16* WvT     = WkT + 8192;                       // 4096
    _Float16* WoT     = WvT + 4096;                       // 4096
    int*      head    = (int*)(WoT + 4096);               // 100000 ints (400 KB)
    int2*     next2   = (int2*)(head + N_NODES);          // 1M int2 (8 MB)

    const int* src = ei;             // edge_index[0]
    const int* dst = ei + N_EDGES;   // edge_index[1]

    const dim3 blk(256);

    prep_kernel<<<dim3(PREP_BLOCKS + HEAD_BLOCKS), blk, 0, stream>>>(
        qw, kw, vw, ow, WqT, WkT, WvT, WoT, head);

    fill_qkv_kernel<<<dim3(QKV_BLOCKS + FILL_BLOCKS), blk, 0, stream>>>(
        src, dst, head, next2,
        x, tf, WqT, WkT, WvT, qb, kb, vb, Qh, KV);

    agg_kernel<<<dim3(AGG_BLOCKS), blk, 0, stream>>>(
        head, next2, (const __half*)Qh, KV, WoT, ob, out);
}

// Round 19
// 128.518 us; speedup vs baseline: 1.0550x; 1.0550x over previous
//
#include <hip/hip_runtime.h>
#include <hip/hip_fp16.h>
#include <math.h>

#define N_NODES 100000
#define N_EDGES 1000000
#define QKV_BLOCKS ((N_NODES + 63) / 64)      // 1563
#define FILL_BLOCKS ((N_EDGES + 255) / 256)   // 3907 (1 edge/thread)
#define PREP_BLOCKS 96                        // 24576 weight elems / 256
#define HEAD_BLOCKS 98                        // 25000 int4 stores / 256
#define AGG_BLOCKS ((N_NODES + 63) / 64)      // 1563 (64 nodes/block)
// IN=64, TD=64, OUT=64, H=4, HD=16

typedef __attribute__((ext_vector_type(8))) _Float16 f16x8;
typedef __attribute__((ext_vector_type(4))) float    f32x4;

// ---------------------------------------------------------------------------
// Dispatch 1: weight transpose+fp16 (96 blocks) + head[]=-1 init (98 blocks).
// WqT/WkT: [64][128]; WvT/WoT: [64][64]. WT[c][k] = w[k*64+c].
// ---------------------------------------------------------------------------
__global__ __launch_bounds__(256) void prep_kernel(
    const float* __restrict__ qw, const float* __restrict__ kw,
    const float* __restrict__ vw, const float* __restrict__ ow,
    _Float16* __restrict__ WqT, _Float16* __restrict__ WkT,
    _Float16* __restrict__ WvT, _Float16* __restrict__ WoT,
    int* __restrict__ head)
{
    if (blockIdx.x < PREP_BLOCKS) {
        const int idx = blockIdx.x * 256 + threadIdx.x;   // 0..24575
        if (idx < 8192) {
            const int c = idx >> 7, k = idx & 127;
            WqT[idx] = (_Float16)qw[k * 64 + c];
        } else if (idx < 16384) {
            const int i = idx - 8192, c = i >> 7, k = i & 127;
            WkT[i] = (_Float16)kw[k * 64 + c];
        } else if (idx < 20480) {
            const int i = idx - 16384, c = i >> 6, k = i & 63;
            WvT[i] = (_Float16)vw[k * 64 + c];
        } else {
            const int i = idx - 20480, c = i >> 6, k = i & 63;
            WoT[i] = (_Float16)ow[k * 64 + c];
        }
    } else {
        const int idx = (blockIdx.x - PREP_BLOCKS) * 256 + threadIdx.x;
        if (idx < N_NODES / 4)                 // 25000 int4 = 100000 ints
            ((int4*)head)[idx] = make_int4(-1, -1, -1, -1);
    }
}

// ---------------------------------------------------------------------------
// Dispatch 2: QKV-MFMA (1563 blocks, first) || linked-list fill (3907 blocks).
// fill: old = atomicExch(&head[d], e); next2[e] = {old, src[e]} (coalesced).
// ~65us = device returning-atomic wall (probed r10-r16: insensitive to
// address spread, op type, ILP, order); qkv's ~45us of compute hides under it.
// qkv: m89-verified MFMA; K/V interleaved as KV[node][128] (K cols 0..63,
// V cols 64..127) for gather locality. fp8-K variant (r18) regressed: 1-byte
// scattered stores re-introduced partial-line write amplification on the
// producer side, outweighing agg's byte savings.
// ---------------------------------------------------------------------------
__global__ __launch_bounds__(256) void fill_qkv_kernel(
    const int* __restrict__ src, const int* __restrict__ dst,
    int* __restrict__ head, int2* __restrict__ next2,
    const float* __restrict__ x, const float* __restrict__ tf,
    const _Float16* __restrict__ WqT, const _Float16* __restrict__ WkT,
    const _Float16* __restrict__ WvT,
    const float* __restrict__ qb, const float* __restrict__ kb,
    const float* __restrict__ vb,
    _Float16* __restrict__ Qh, _Float16* __restrict__ KV)
{
    __shared__ _Float16 xt[64][128];     // 16 KB (fill blocks ignore it)
    const int t = threadIdx.x;

    if (blockIdx.x >= QKV_BLOCKS) {
        const int e = (blockIdx.x - QKV_BLOCKS) * 256 + t;
        if (e < N_EDGES) {
            const int d  = dst[e];
            const int sv = src[e];
            const int old = atomicExch(&head[d], e);
            next2[e] = make_int2(old, sv);
        }
        return;
    }

    const int base = blockIdx.x * 64;

    // stage [x|tf] -> LDS f16, swizzled groups
    {
        const int j = t & 15;
        #pragma unroll
        for (int i = 0; i < 4; ++i) {
            const int r = (t >> 4) + 16 * i;
            int node = base + r;
            if (node >= N_NODES) node = N_NODES - 1;   // clamp; stores guarded
            const float* p = (j < 8) ? (x  + (size_t)node * 64 + 8 * j)
                                     : (tf + (size_t)node * 64 + 8 * (j - 8));
            const float4 lo = ((const float4*)p)[0];
            const float4 hi = ((const float4*)p)[1];
            f16x8 h = { (_Float16)lo.x, (_Float16)lo.y, (_Float16)lo.z,
                        (_Float16)lo.w, (_Float16)hi.x, (_Float16)hi.y,
                        (_Float16)hi.z, (_Float16)hi.w };
            const int js = j ^ (r & 15);
            *(f16x8*)&xt[r][js * 8] = h;
        }
    }

    const int wave = t >> 6;
    const int lane = t & 63;
    const int lrow = lane & 15;
    const int lgrp = lane >> 4;
    const int cw   = wave * 16;

    f16x8 bq[4], bk[4], bv[2];
    const float biasq = qb[cw + lrow];
    const float biask = kb[cw + lrow];
    const float biasv = vb[cw + lrow];
    {
        const size_t rq = (size_t)(cw + lrow) * 128 + lgrp * 8;
        #pragma unroll
        for (int kt = 0; kt < 4; ++kt) {
            bq[kt] = *(const f16x8*)&WqT[rq + kt * 32];
            bk[kt] = *(const f16x8*)&WkT[rq + kt * 32];
        }
        const size_t rv = (size_t)(cw + lrow) * 64 + lgrp * 8;
        #pragma unroll
        for (int kt = 0; kt < 2; ++kt)
            bv[kt] = *(const f16x8*)&WvT[rv + kt * 32];
    }
    __syncthreads();

    #pragma unroll
    for (int rt = 0; rt < 4; ++rt) {
        f16x8 a[4];
        const int r = rt * 16 + lrow;
        #pragma unroll
        for (int kt = 0; kt < 4; ++kt) {
            const int js = (kt * 4 + lgrp) ^ lrow;
            a[kt] = *(const f16x8*)&xt[r][js * 8];
        }
        f32x4 accq = {0.f, 0.f, 0.f, 0.f};
        f32x4 acck = {0.f, 0.f, 0.f, 0.f};
        f32x4 accv = {0.f, 0.f, 0.f, 0.f};
        #pragma unroll
        for (int kt = 0; kt < 4; ++kt) {
            accq = __builtin_amdgcn_mfma_f32_16x16x32_f16(a[kt], bq[kt], accq, 0, 0, 0);
            acck = __builtin_amdgcn_mfma_f32_16x16x32_f16(a[kt], bk[kt], acck, 0, 0, 0);
        }
        #pragma unroll
        for (int kt = 0; kt < 2; ++kt)
            accv = __builtin_amdgcn_mfma_f32_16x16x32_f16(a[kt], bv[kt], accv, 0, 0, 0);
        #pragma unroll
        for (int rr = 0; rr < 4; ++rr) {
            const int node = base + rt * 16 + lgrp * 4 + rr;
            if (node < N_NODES) {
                Qh[(size_t)node * 64 + cw + lrow]        = (_Float16)(accq[rr] + biasq);
                KV[(size_t)node * 128 + cw + lrow]       = (_Float16)(acck[rr] + biask);
                KV[(size_t)node * 128 + 64 + cw + lrow]  = (_Float16)(accv[rr] + biasv);
            }
        }
    }
}

// ---------------------------------------------------------------------------
// Dispatch 3: gather-aggregate + normalize + MFMA output GEMM, fused.
// 64 nodes/block, 4 waves x 16 nodes, work-pool load balancing (r15) +
// 1-deep next2 prefetch (r17). agg is pinned at ~64us across three
// scheduling structures (r14/r15/r17) at ~170MB FETCH / ~3TB/s: random-
// gather throughput wall.
// ---------------------------------------------------------------------------
__global__ __launch_bounds__(256) void agg_kernel(
    const int* __restrict__ head, const int2* __restrict__ next2,
    const __half* __restrict__ Qh, const __half* __restrict__ KVh,
    const _Float16* __restrict__ WoT, const float* __restrict__ ob,
    float* __restrict__ out)
{
    __shared__ _Float16 aggh[64][64];     // 8 KB
    __shared__ int pool[4];
    const int t    = threadIdx.x;
    const int wave = t >> 6;
    const int lane = t & 63;
    const int g    = lane >> 3;        // slot 0..7
    const int s    = lane & 7;         // sublane: cols 8s..8s+7
    const int lrow = lane & 15;        // MFMA A-row / D-col
    const int lgrp = lane >> 4;        // MFMA k-group
    const int cw   = wave * 16;        // out col tile base
    const int nb   = blockIdx.x * 64;
    const int wbase = wave * 16;       // wave's row base

    if (lane == 0) pool[wave] = 8;

    f16x8 bo0, bo1;
    {
        const size_t ro = (size_t)(cw + lrow) * 64 + lgrp * 8;
        bo0 = *(const f16x8*)&WoT[ro];
        bo1 = *(const f16x8*)&WoT[ro + 32];
    }
    const float biaso = ob[cw + lrow];
    __syncthreads();                   // pool init visible

    const uint4* __restrict__ Q4  = (const uint4*)Qh;
    const uint4* __restrict__ KV4 = (const uint4*)KVh;

    int   idx  = g;
    int   cur  = nb + wbase + idx;
    int   e    = (cur < N_NODES) ? head[cur] : -1;
    int2  sn   = next2[(e >= 0) ? e : 0];   // current hop's {next,src} (dummy-safe)
    bool  done = false;
    float acc[8] = {0.f, 0.f, 0.f, 0.f, 0.f, 0.f, 0.f, 0.f};
    float ssum = 0.f;
    float qf[8];
    {
        const int qn = (cur < N_NODES) ? cur : 0;
        const uint4 qu = Q4[(size_t)qn * 8 + s];
        const __half2* qh = (const __half2*)&qu;
        #pragma unroll
        for (int j = 0; j < 4; ++j) {
            const float2 a = __half22float2(qh[j]);
            qf[2 * j] = a.x; qf[2 * j + 1] = a.y;
        }
    }

    for (;;) {
        while (e < 0 && !done) {
            const float inv = (ssum > 0.f) ? (1.0f / ssum) : 0.0f;
            const int r = wbase + idx;
            f16x8 h = { (_Float16)(acc[0] * inv), (_Float16)(acc[1] * inv),
                        (_Float16)(acc[2] * inv), (_Float16)(acc[3] * inv),
                        (_Float16)(acc[4] * inv), (_Float16)(acc[5] * inv),
                        (_Float16)(acc[6] * inv), (_Float16)(acc[7] * inv) };
            *(f16x8*)&aggh[r][(s ^ (r & 7)) * 8] = h;

            int tkt = 0;
            if (s == 0) tkt = atomicAdd(&pool[wave], 1);
            tkt = __shfl(tkt, g * 8);
            if (tkt < 16) {
                idx = tkt;
                cur = nb + wbase + idx;
                e   = (cur < N_NODES) ? head[cur] : -1;
                sn  = next2[(e >= 0) ? e : 0];
                const int qn = (cur < N_NODES) ? cur : 0;
                const uint4 qu = Q4[(size_t)qn * 8 + s];
                const __half2* qh = (const __half2*)&qu;
                #pragma unroll
                for (int j = 0; j < 4; ++j) {
                    const float2 a = __half22float2(qh[j]);
                    qf[2 * j] = a.x; qf[2 * j + 1] = a.y;
                }
                #pragma unroll
                for (int j = 0; j < 8; ++j) acc[j] = 0.f;
                ssum = 0.f;
            } else {
                done = true;
            }
        }
        if (__all(done)) break;

        const bool act = (e >= 0);
        const int  sv  = act ? sn.y : 0;     // src node (dummy 0 if inactive)
        const int  en  = act ? sn.x : -1;    // next edge in chain

        // PREFETCH next hop's {next,src}; overlaps the K/V gather below
        const int2 snn = next2[(en >= 0) ? en : 0];

        const uint4 ku = KV4[(size_t)sv * 16 + s];       // K slice
        const uint4 vu = KV4[(size_t)sv * 16 + 8 + s];   // V slice (adjacent)

        float kf[8], vf[8];
        {
            const __half2* kh = (const __half2*)&ku;
            const __half2* vh = (const __half2*)&vu;
            #pragma unroll
            for (int j = 0; j < 4; ++j) {
                const float2 a = __half22float2(kh[j]);
                const float2 b = __half22float2(vh[j]);
                kf[2 * j] = a.x; kf[2 * j + 1] = a.y;
                vf[2 * j] = b.x; vf[2 * j + 1] = b.y;
            }
        }
        float dq = qf[0] * kf[0] + qf[1] * kf[1] + qf[2] * kf[2] + qf[3] * kf[3]
                 + qf[4] * kf[4] + qf[5] * kf[5] + qf[6] * kf[6] + qf[7] * kf[7];
        dq += __shfl_xor(dq, 1);             // pair (2h,2h+1): full head dot
        const float p = act ? __expf(dq * 0.25f) : 0.f;   // 1/sqrt(16)
        ssum += p;
        #pragma unroll
        for (int j = 0; j < 8; ++j) acc[j] = fmaf(p, vf[j], acc[j]);

        e  = act ? en : -1;
        sn = snn;
    }
    __syncthreads();

    // out tile [64 nodes][64 cols] = aggh @ WoT ; wave w -> cols 16w..16w+15
    #pragma unroll
    for (int rt = 0; rt < 4; ++rt) {
        const int r = rt * 16 + lrow;
        f16x8 a0 = *(const f16x8*)&aggh[r][((lgrp)     ^ (lrow & 7)) * 8];
        f16x8 a1 = *(const f16x8*)&aggh[r][((4 + lgrp) ^ (lrow & 7)) * 8];
        f32x4 acco = {0.f, 0.f, 0.f, 0.f};
        acco = __builtin_amdgcn_mfma_f32_16x16x32_f16(a0, bo0, acco, 0, 0, 0);
        acco = __builtin_amdgcn_mfma_f32_16x16x32_f16(a1, bo1, acco, 0, 0, 0);
        #pragma unroll
        for (int rr = 0; rr < 4; ++rr) {
            const int n = nb + rt * 16 + lgrp * 4 + rr;
            if (n < N_NODES)
                out[(size_t)n * 64 + cw + lrow] = acco[rr] + biaso;
        }
    }
}

// ---------------------------------------------------------------------------
extern "C" void kernel_launch(void* const* d_in, const int* in_sizes, int n_in,
                              void* d_out, int out_size, void* d_ws, size_t ws_size,
                              hipStream_t stream) {
    const float* x  = (const float*)d_in[0];
    const float* tf = (const float*)d_in[1];
    const int*   ei = (const int*)  d_in[2];
    const float* qw = (const float*)d_in[3];
    const float* qb = (const float*)d_in[4];
    const float* kw = (const float*)d_in[5];
    const float* kb = (const float*)d_in[6];
    const float* vw = (const float*)d_in[7];
    const float* vb = (const float*)d_in[8];
    const float* ow = (const float*)d_in[9];
    const float* ob = (const float*)d_in[10];
    float* out = (float*)d_out;

    char* ws = (char*)d_ws;
    const size_t hf = (size_t)N_NODES * 64 * sizeof(_Float16);  // 12.8 MB

    _Float16* Qh      = (_Float16*)(ws);
    _Float16* KV      = (_Float16*)(ws + hf);            // 25.6 MB interleaved
    _Float16* WqT     = (_Float16*)(ws + 3 * hf);        // 8192 halves
    _Float16* WkT     = WqT + 8192;                       // 8192
    _Float16* WvT     = WkT + 8192;                       // 4096
    _Float16* WoT     = WvT + 4096;                       // 4096
    int*      head    = (int*)(WoT + 4096);               // 100000 ints (400 KB)
    int2*     next2   = (int2*)(head + N_NODES);          // 1M int2 (8 MB)

    const int* src = ei;             // edge_index[0]
    const int* dst = ei + N_EDGES;   // edge_index[1]

    const dim3 blk(256);

    prep_kernel<<<dim3(PREP_BLOCKS + HEAD_BLOCKS), blk, 0, stream>>>(
        qw, kw, vw, ow, WqT, WkT, WvT, WoT, head);

    fill_qkv_kernel<<<dim3(QKV_BLOCKS + FILL_BLOCKS), blk, 0, stream>>>(
        src, dst, head, next2,
        x, tf, WqT, WkT, WvT, qb, kb, vb, Qh, KV);

    agg_kernel<<<dim3(AGG_BLOCKS), blk, 0, stream>>>(
        head, next2, (const __half*)Qh, (const __half*)KV, WoT, ob, out);
}